// Round 14
// baseline (522.152 us; speedup 1.0000x reference)
//
#include <hip/hip_runtime.h>

// ---------------- CSR construction ----------------

__global__ void count_kernel(const int* __restrict__ dst, int* __restrict__ cnt, int E) {
    int e = blockIdx.x * blockDim.x + threadIdx.x;
    if (e < E) atomicAdd(&cnt[dst[e]], 1);
}

__global__ void scan1(const int* __restrict__ cnt, int* __restrict__ offs,
                      int* __restrict__ partials, int N) {
    __shared__ int s[256];
    int t = threadIdx.x;
    int i = blockIdx.x * 256 + t;
    int v = (i < N) ? cnt[i] : 0;
    s[t] = v;
    __syncthreads();
    #pragma unroll
    for (int d = 1; d < 256; d <<= 1) {
        int tv = (t >= d) ? s[t - d] : 0;
        __syncthreads();
        s[t] += tv;
        __syncthreads();
    }
    if (i < N) offs[i] = s[t] - v;   // block-local exclusive
    if (t == 255) partials[blockIdx.x] = s[255];
}

__global__ void scan2(int* partials, int nb) {
    __shared__ int s[256];
    int t = threadIdx.x;
    int v = (t < nb) ? partials[t] : 0;
    s[t] = v;
    __syncthreads();
    #pragma unroll
    for (int d = 1; d < 256; d <<= 1) {
        int tv = (t >= d) ? s[t - d] : 0;
        __syncthreads();
        s[t] += tv;
        __syncthreads();
    }
    if (t < nb) partials[t] = s[t] - v;  // exclusive block bases
}

__global__ void scan3(const int* __restrict__ cnt, int* __restrict__ offs,
                      int* __restrict__ offwork, float* __restrict__ dinv,
                      const int* __restrict__ partials, int N, int E) {
    int i = blockIdx.x * 256 + threadIdx.x;
    if (i < N) {
        int o = offs[i] + partials[blockIdx.x];
        offs[i] = o;
        offwork[i] = o;
        dinv[i] = rsqrtf((float)cnt[i] + 1.0f);  // deg = in-degree + self-loop
    }
    if (i == 0) offs[N] = E;
}

__global__ void scatter_kernel(const int* __restrict__ src, const int* __restrict__ dst,
                               int* __restrict__ offwork, int* __restrict__ csr, int E) {
    int e = blockIdx.x * blockDim.x + threadIdx.x;
    if (e < E) {
        int pos = atomicAdd(&offwork[dst[e]], 1);
        csr[pos] = src[e];
    }
}

// ---------------- fp32 GEMM: Y[M,128] = X[M,128] @ W[128,128] (+bias, relu, rowscale) ----
// BM=64, BN=128, BK=32, 128 threads (2 waves), thread tile 8 rows x 8 cols.
// 4 ds_read_b128 per 64 FMA (vs 3 per 32 in the 256-thr version); A-reads broadcast,
// B-reads split-column (tx*4 and 64+tx*4) -> 2-way bank aliasing only (free).

__global__ __launch_bounds__(128, 2) void gemm128(const float* __restrict__ X,
                                                  const float* __restrict__ W,
                                                  const float* __restrict__ bias,
                                                  const float* __restrict__ rowscale,
                                                  float* __restrict__ Y,
                                                  int M, int relu) {
    __shared__ float As[32][68];    // k-major: As[k][row]
    __shared__ float Bs[32][132];   // Bs[k][col]

    int tid = threadIdx.x;          // 0..127
    int tx = tid & 15;              // col group 0..15
    int ty = tid >> 4;              // row group 0..7
    int row0 = blockIdx.x * 64;

    float acc[8][8];
    #pragma unroll
    for (int r = 0; r < 8; r++)
        #pragma unroll
        for (int c = 0; c < 8; c++) acc[r][c] = 0.0f;

    int lr = tid >> 1;              // A row 0..63
    int kc = (tid & 1) * 16;        // A k-chunk base (0 or 16)
    int wr = tid >> 2;              // B k-row 0..31
    int wc = (tid & 3) * 32;        // B col-chunk base

    for (int k0 = 0; k0 < 128; k0 += 32) {
        // register-prestage global loads
        float4 xa[4];
        int grow = row0 + lr;
        if (grow < M) {
            #pragma unroll
            for (int i = 0; i < 4; i++)
                xa[i] = *(const float4*)&X[(size_t)grow * 128 + k0 + kc + i * 4];
        } else {
            #pragma unroll
            for (int i = 0; i < 4; i++) xa[i] = make_float4(0.f, 0.f, 0.f, 0.f);
        }
        float4 wv[8];
        #pragma unroll
        for (int i = 0; i < 8; i++)
            wv[i] = *(const float4*)&W[(size_t)(k0 + wr) * 128 + wc + i * 4];

        __syncthreads();   // previous iteration's compute done
        #pragma unroll
        for (int i = 0; i < 4; i++) {
            As[kc + i * 4 + 0][lr] = xa[i].x;
            As[kc + i * 4 + 1][lr] = xa[i].y;
            As[kc + i * 4 + 2][lr] = xa[i].z;
            As[kc + i * 4 + 3][lr] = xa[i].w;
        }
        #pragma unroll
        for (int i = 0; i < 8; i++)
            *(float4*)&Bs[wr][wc + i * 4] = wv[i];
        __syncthreads();

        #pragma unroll
        for (int k = 0; k < 32; k++) {
            float4 a0 = *(const float4*)&As[k][ty * 8];
            float4 a1 = *(const float4*)&As[k][ty * 8 + 4];
            float4 b0 = *(const float4*)&Bs[k][tx * 4];
            float4 b1 = *(const float4*)&Bs[k][64 + tx * 4];
            float av[8] = {a0.x, a0.y, a0.z, a0.w, a1.x, a1.y, a1.z, a1.w};
            float bv[8] = {b0.x, b0.y, b0.z, b0.w, b1.x, b1.y, b1.z, b1.w};
            #pragma unroll
            for (int r = 0; r < 8; r++)
                #pragma unroll
                for (int c = 0; c < 8; c++)
                    acc[r][c] = fmaf(av[r], bv[c], acc[r][c]);
        }
    }

    #pragma unroll
    for (int r = 0; r < 8; r++) {
        int grow = row0 + ty * 8 + r;
        if (grow < M) {
            float scale = rowscale ? rowscale[grow] : 1.0f;
            float o[8];
            #pragma unroll
            for (int c = 0; c < 8; c++) o[c] = acc[r][c];
            if (bias) {
                #pragma unroll
                for (int c = 0; c < 4; c++) {
                    o[c]     += bias[tx * 4 + c];
                    o[c + 4] += bias[64 + tx * 4 + c];
                }
            }
            #pragma unroll
            for (int c = 0; c < 8; c++) o[c] *= scale;
            if (relu) {
                #pragma unroll
                for (int c = 0; c < 8; c++) o[c] = fmaxf(o[c], 0.0f);
            }
            float4 o0 = make_float4(o[0], o[1], o[2], o[3]);
            float4 o1 = make_float4(o[4], o[5], o[6], o[7]);
            *(float4*)&Y[(size_t)grow * 128 + tx * 4]      = o0;
            *(float4*)&Y[(size_t)grow * 128 + 64 + tx * 4] = o1;
        }
    }
}

// ---------------- aggregation: 1 wave per node, float4 per lane-half ----------------
// Lanes 0-31 cover the 512B row (32 x float4) for EVEN neighbors, lanes 32-63 for
// ODD neighbors (same list -> no divergence). Combine halves with shfl_xor(32).
// mode 0: U[v] = H[v] + sum H[nbr]           (GIN pre-linear)
// mode 1: B[v] = relu((A[v]+sum A[nbr])*dinv[v] + b0)   (GCN, A pre-scaled by dinv)

__global__ __launch_bounds__(256) void agg_kernel(const float* __restrict__ A,
                                                  float* __restrict__ B,
                                                  const int* __restrict__ offs,
                                                  const int* __restrict__ csr,
                                                  const float* __restrict__ dinv,
                                                  const float* __restrict__ b0,
                                                  int N, int mode) {
    int v = blockIdx.x * 4 + (threadIdx.x >> 6);
    if (v >= N) return;
    int lane = threadIdx.x & 63;
    int half = lane >> 5;
    int l32 = lane & 31;
    const float4* Ap = (const float4*)A;

    float4 acc;
    if (half == 0) {
        acc = Ap[(size_t)v * 32 + l32];       // self term counted once
    } else {
        acc = make_float4(0.f, 0.f, 0.f, 0.f);
    }

    int i0 = offs[v], i1 = offs[v + 1];
    int p = i0 + half;                        // this half's first neighbor, stride 2
    // 4 neighbors per half per iteration -> 8 total, 64B/lane in flight
    for (; p + 6 < i1; p += 8) {
        int s0 = csr[p + 0];
        int s1 = csr[p + 2];
        int s2 = csr[p + 4];
        int s3 = csr[p + 6];
        float4 a0 = Ap[(size_t)s0 * 32 + l32];
        float4 a1 = Ap[(size_t)s1 * 32 + l32];
        float4 a2 = Ap[(size_t)s2 * 32 + l32];
        float4 a3 = Ap[(size_t)s3 * 32 + l32];
        acc.x += a0.x + a1.x + a2.x + a3.x;
        acc.y += a0.y + a1.y + a2.y + a3.y;
        acc.z += a0.z + a1.z + a2.z + a3.z;
        acc.w += a0.w + a1.w + a2.w + a3.w;
    }
    for (; p < i1; p += 2) {
        float4 a = Ap[(size_t)csr[p] * 32 + l32];
        acc.x += a.x; acc.y += a.y; acc.z += a.z; acc.w += a.w;
    }

    // combine even/odd halves (lane i <-> lane i^32)
    acc.x += __shfl_xor(acc.x, 32, 64);
    acc.y += __shfl_xor(acc.y, 32, 64);
    acc.z += __shfl_xor(acc.z, 32, 64);
    acc.w += __shfl_xor(acc.w, 32, 64);

    if (half == 0) {
        float4 r = acc;
        if (mode == 1) {
            float dv = dinv[v];
            float4 bb = ((const float4*)b0)[l32];
            r.x = fmaxf(r.x * dv + bb.x, 0.0f);
            r.y = fmaxf(r.y * dv + bb.y, 0.0f);
            r.z = fmaxf(r.z * dv + bb.z, 0.0f);
            r.w = fmaxf(r.w * dv + bb.w, 0.0f);
        }
        ((float4*)B)[(size_t)v * 32 + l32] = r;
    }
}

// ---------------- pooling + head ----------------

// Partial pooled sums: each block scans 128 sorted rows, run-length segments by
// graph id, one atomicAdd per (segment, feature).
__global__ void pool_partial(const float* __restrict__ H, const int* __restrict__ batch,
                             float* __restrict__ S, int N) {
    int r0 = blockIdx.x * 128;
    int r1 = min(r0 + 128, N);
    if (r0 >= N) return;
    int t = threadIdx.x;  // 128 threads, one feature each
    float acc = 0.0f;
    int curg = batch[r0];
    for (int r = r0; r < r1; r++) {
        int g = batch[r];
        if (g != curg) {
            atomicAdd(&S[curg * 128 + t], acc);
            acc = 0.0f;
            curg = g;
        }
        acc += H[r * 128 + t];
    }
    atomicAdd(&S[curg * 128 + t], acc);
}

// g = relu((S[g]/cnt) @ Wh1 + bh1):  [G,128] @ [128,256]; graph bounds inlined.
__global__ void head1(const float* __restrict__ S, const int* __restrict__ batch,
                      const float* __restrict__ W, const float* __restrict__ b,
                      float* __restrict__ Y, int N, int G) {
    __shared__ float m[128];
    __shared__ int bound[2];
    int g = blockIdx.x;
    int j = threadIdx.x;  // 256
    if (j < 2) {
        int target = g + j;
        int lo = 0, hi = N;
        while (lo < hi) {
            int mid = (lo + hi) >> 1;
            if (batch[mid] < target) lo = mid + 1; else hi = mid;
        }
        bound[j] = lo;
    }
    __syncthreads();
    int n = bound[1] - bound[0];
    float inv = 1.0f / (float)(n > 0 ? n : 1);
    if (j < 128) m[j] = S[g * 128 + j] * inv;
    __syncthreads();
    float acc = b[j];
    #pragma unroll 8
    for (int k = 0; k < 128; k++) acc = fmaf(m[k], W[k * 256 + j], acc);
    Y[g * 256 + j] = fmaxf(acc, 0.0f);
}

// out = g @ Wh2 + bh2:  [G,256] @ [256,128]
__global__ void head2(const float* __restrict__ Gx, const float* __restrict__ W,
                      const float* __restrict__ b, float* __restrict__ out) {
    __shared__ float m[256];
    int g = blockIdx.x;
    int j = threadIdx.x;  // 128
    m[j] = Gx[g * 256 + j];
    m[j + 128] = Gx[g * 256 + 128 + j];
    __syncthreads();
    float acc = b[j];
    #pragma unroll 8
    for (int k = 0; k < 256; k++) acc = fmaf(m[k], W[k * 128 + j], acc);
    out[g * 128 + j] = acc;
}

// ---------------- launch ----------------

extern "C" void kernel_launch(void* const* d_in, const int* in_sizes, int n_in,
                              void* d_out, int out_size, void* d_ws, size_t ws_size,
                              hipStream_t stream) {
    const float* x     = (const float*)d_in[0];
    const int*   ei    = (const int*)d_in[1];
    const int*   batch = (const int*)d_in[2];
    const float* W0  = (const float*)d_in[3];
    const float* b0  = (const float*)d_in[4];
    const float* Wg1 = (const float*)d_in[5];
    const float* bg1 = (const float*)d_in[6];
    const float* Wg2 = (const float*)d_in[7];
    const float* bg2 = (const float*)d_in[8];
    const float* Wh1 = (const float*)d_in[9];
    const float* bh1 = (const float*)d_in[10];
    const float* Wh2 = (const float*)d_in[11];
    const float* bh2 = (const float*)d_in[12];

    int N = in_sizes[2];          // batch has N elements
    int E = in_sizes[1] / 2;      // edge_index is (2,E)
    int G = out_size / 128;       // output is (G, 128)
    const int* srcp = ei;
    const int* dstp = ei + E;

    // workspace carve (256B aligned)
    char* w = (char*)d_ws;
    auto take = [&](size_t bytes) -> void* {
        void* p = (void*)w;
        w += (bytes + 255) & ~(size_t)255;
        return p;
    };
    float* A        = (float*)take((size_t)N * 128 * 4);
    float* Bf       = (float*)take((size_t)N * 128 * 4);
    int*   csr      = (int*)take((size_t)E * 4);
    int*   offs     = (int*)take((size_t)(N + 1) * 4);
    int*   offw     = (int*)take((size_t)N * 4);
    int*   cnt      = (int*)take((size_t)N * 4);
    float* dinv     = (float*)take((size_t)N * 4);
    int*   partials = (int*)take(1024);
    float* S        = (float*)take((size_t)G * 128 * 4);
    float* Gh       = (float*)take((size_t)G * 256 * 4);

    int nb = (N + 255) / 256;

    // CSR build
    hipMemsetAsync(cnt, 0, (size_t)N * 4, stream);
    hipMemsetAsync(S, 0, (size_t)G * 128 * 4, stream);
    count_kernel<<<(E + 255) / 256, 256, 0, stream>>>(dstp, cnt, E);
    scan1<<<nb, 256, 0, stream>>>(cnt, offs, partials, N);
    scan2<<<1, 256, 0, stream>>>(partials, nb);
    scan3<<<nb, 256, 0, stream>>>(cnt, offs, offw, dinv, partials, N, E);
    scatter_kernel<<<(E + 255) / 256, 256, 0, stream>>>(srcp, dstp, offw, csr, E);

    // GCN: A = (x@W0) * dinv[row] ; Bf = relu((A[v]+sum A[nbr]) * dinv[v] + b0)
    gemm128<<<(N + 63) / 64, 128, 0, stream>>>(x, W0, nullptr, dinv, A, N, 0);
    agg_kernel<<<(N + 3) / 4, 256, 0, stream>>>(A, Bf, offs, csr, dinv, b0, N, 1);

    // GIN 1
    agg_kernel<<<(N + 3) / 4, 256, 0, stream>>>(Bf, A, offs, csr, nullptr, nullptr, N, 0);
    gemm128<<<(N + 63) / 64, 128, 0, stream>>>(A, Wg1, bg1, nullptr, Bf, N, 1);

    // GIN 2
    agg_kernel<<<(N + 3) / 4, 256, 0, stream>>>(Bf, A, offs, csr, nullptr, nullptr, N, 0);
    gemm128<<<(N + 63) / 64, 128, 0, stream>>>(A, Wg2, bg2, nullptr, Bf, N, 1);

    // pool + head
    pool_partial<<<(N + 127) / 128, 128, 0, stream>>>(Bf, batch, S, N);
    head1<<<G, 256, 0, stream>>>(S, batch, Wh1, bh1, Gh, N, G);
    head2<<<G, 128, 0, stream>>>(Gh, Wh2, bh2, (float*)d_out);
}